// Round 8
// baseline (434.546 us; speedup 1.0000x reference)
//
#include <hip/hip_runtime.h>

// ---------------------------------------------------------------------------
// LinformerAttention on MI355X (gfx950) — round 15.
// B=4, N=4096, C=1024, H=16, K_LM=256, d=64.
// Baseline r14: 420.9 us. NOTE: r7 bench ran at ~13% lower clock (qkv
// 107->123.7 us with identical code+counters; hbm_gbps -13%) — cross-round
// absolute deltas carry that noise; r14's lm pipeline was a real win
// normalized (~15-25 us).
// Round-15 single experiment: lm_gemm kt-merge.
//   Old: 1024 blocks (kt,s,z); the 4 kt-blocks of one (z,s) re-stage the
//   SAME kT/vT slices 4x -> 393 MB staged.
//   New: 256 blocks (z,s), 512 thr / 8 waves, full 256 landmark rows per
//   block -> 197 MB staged (-50%), zero grid tail (1 block/CU).
//   r9 trap (1/CU + prefetch-1 < HBM latency) countered by 3-buffer
//   prefetch-distance-2 pipeline: 9 loads in flight, vmcnt(6); LDS 72 KB.
//   Same n-summation order -> bit-identical partials; lm_reduce untouched.
// Everything else byte-identical to r14.
// ---------------------------------------------------------------------------

typedef unsigned short ushort_t;
typedef float f32x4 __attribute__((ext_vector_type(4)));
typedef __bf16 bf16x8 __attribute__((ext_vector_type(8)));
typedef unsigned short ushort8 __attribute__((ext_vector_type(8)));
typedef unsigned short ushort4_t __attribute__((ext_vector_type(4)));

__device__ inline ushort_t f2bf(float f) {
  unsigned int u = __float_as_uint(f);
  u += 0x7fff + ((u >> 16) & 1);   // RNE
  return (ushort_t)(u >> 16);
}

// async global -> LDS, 16 B per lane. LDS dest is wave-uniform base + lane*16.
__device__ inline void gload_lds16(const ushort_t* g, ushort_t* l) {
  __builtin_amdgcn_global_load_lds(
      (const __attribute__((address_space(1))) void*)g,
      (__attribute__((address_space(3))) void*)l, 16, 0, 0);
}

// --------------- fused f32 -> bf16 convert of all four inputs --------------
__global__ __launch_bounds__(256) void cvt_all(
    const float* __restrict__ x,  ushort_t* __restrict__ xo,
    const float* __restrict__ w1, ushort_t* __restrict__ w1o,
    const float* __restrict__ e,  ushort_t* __restrict__ eo,
    const float* __restrict__ w2, ushort_t* __restrict__ w2o) {
  // float4 chunk counts: x 4194304 | Wqkv 786432 | E 4194304 | Wproj 262144
  int i = blockIdx.x * blockDim.x + threadIdx.x;
  const float* in; ushort_t* out; int idx;
  if (i < 4194304)               { in = x;  out = xo;  idx = i; }
  else if (i < 4980736)          { in = w1; out = w1o; idx = i - 4194304; }
  else if (i < 9175040)          { in = e;  out = eo;  idx = i - 4980736; }
  else                           { in = w2; out = w2o; idx = i - 9175040; }
  float4 v = ((const float4*)in)[idx];
  ushort4_t o;
  o.x = f2bf(v.x); o.y = f2bf(v.y); o.z = f2bf(v.z); o.w = f2bf(v.w);
  ((ushort4_t*)out)[idx] = o;
}

// ===========================================================================
// 256x256 8-phase pipelined GEMM core (C = A @ B^T), K = 1024, bf16 in.
// (r13 schedule, verified: A0 held in regs, 24 ds_read_b128/wave/tile floor.)
// ===========================================================================

#define BARX __builtin_amdgcn_s_barrier()
#define WVM(n) do { asm volatile("s_waitcnt vmcnt(" #n ")" ::: "memory"); \
                    __builtin_amdgcn_sched_barrier(0); } while (0)
#define WLG  do { asm volatile("s_waitcnt lgkmcnt(0)" ::: "memory"); \
                  __builtin_amdgcn_sched_barrier(0); } while (0)

#define STG_A(h, slot, tt) do { \
    gload_lds16(sA[h][0] + (tt) * 64, (ushort_t*)(smem + (slot) * 32768 + (h) * 16384 + (w * 2 + 0) * 1024)); \
    gload_lds16(sA[h][1] + (tt) * 64, (ushort_t*)(smem + (slot) * 32768 + (h) * 16384 + (w * 2 + 1) * 1024)); \
  } while (0)
#define STG_B(h, slot, tt) do { \
    gload_lds16(sB[h][0] + (tt) * 64, (ushort_t*)(smem + 65536 + (slot) * 32768 + (h) * 16384 + (w * 2 + 0) * 1024)); \
    gload_lds16(sB[h][1] + (tt) * 64, (ushort_t*)(smem + 65536 + (slot) * 32768 + (h) * 16384 + (w * 2 + 1) * 1024)); \
  } while (0)

#define RD_A(mh, AF) do { \
    const char* ba_ = smem + sl * 32768 + ((mh) * 128 + wm * 64 + l15) * 128; \
    _Pragma("unroll") for (int i_ = 0; i_ < 4; i_++) { \
      AF[i_][0] = *(const bf16x8*)(ba_ + i_ * 2048 + cs0); \
      AF[i_][1] = *(const bf16x8*)(ba_ + i_ * 2048 + cs1); } \
  } while (0)
#define RD_B(nh) do { \
    const char* bb_ = smem + 65536 + sl * 32768 + ((nh) * 128 + wn * 32 + l15) * 128; \
    _Pragma("unroll") for (int j_ = 0; j_ < 2; j_++) { \
      bF[j_][0] = *(const bf16x8*)(bb_ + j_ * 2048 + cs0); \
      bF[j_][1] = *(const bf16x8*)(bb_ + j_ * 2048 + cs1); } \
  } while (0)

#define MQ(mh, nh, AF) do { \
    _Pragma("unroll") for (int i_ = 0; i_ < 4; i_++) \
    _Pragma("unroll") for (int j_ = 0; j_ < 2; j_++) { \
      acc[(mh) * 4 + i_][(nh) * 2 + j_] = __builtin_amdgcn_mfma_f32_16x16x32_bf16( \
          AF[i_][0], bF[j_][0], acc[(mh) * 4 + i_][(nh) * 2 + j_], 0, 0, 0); \
      acc[(mh) * 4 + i_][(nh) * 2 + j_] = __builtin_amdgcn_mfma_f32_16x16x32_bf16( \
          AF[i_][1], bF[j_][1], acc[(mh) * 4 + i_][(nh) * 2 + j_], 0, 0, 0); } \
  } while (0)

__device__ __attribute__((always_inline)) inline void pipe256(
    const ushort_t* __restrict__ Ag, const ushort_t* __restrict__ Bg,
    long long m0, long long n0, char* smem, f32x4 acc[8][4]) {
  const int tid = threadIdx.x, lane = tid & 63, w = tid >> 6;
  const int l15 = lane & 15, quad = lane >> 4;
  const int wm = w >> 2, wn = w & 3;
  const int sw = l15 & 7;
  const int K = 1024;
  // swizzled ds_read byte offsets within a 128 B row, for k-step 0 / 1
  const int cs0 = ((0 * 4 + quad) ^ sw) << 4;
  const int cs1 = ((1 * 4 + quad) ^ sw) << 4;
  // staging source: lane L of chunk c=(w*2+q) covers LDS row c*8+(L>>3),
  // slot L&7 -> global k-chunk (L&7)^((L>>3)&7)  (row&7 == (L>>3)&7).
  const int lr8 = lane >> 3;
  const int sdat = ((lane & 7) ^ lr8) * 8;
  const ushort_t* sA[2][2];
  const ushort_t* sB[2][2];
#pragma unroll
  for (int h = 0; h < 2; h++)
#pragma unroll
    for (int q = 0; q < 2; q++) {
      sA[h][q] = Ag + (m0 + h * 128 + (w * 2 + q) * 8 + lr8) * K + sdat;
      sB[h][q] = Bg + (n0 + h * 128 + (w * 2 + q) * 8 + lr8) * K + sdat;
    }

  const f32x4 zz = {0.f, 0.f, 0.f, 0.f};
#pragma unroll
  for (int i = 0; i < 8; i++)
#pragma unroll
    for (int j = 0; j < 4; j++) acc[i][j] = zz;

  bf16x8 aF0[4][2];  // A half 0 — read in ph0, HELD through ph3
  bf16x8 aF1[4][2];  // A half 1 — read in ph1, used ph1/ph2
  bf16x8 bF[2][2];   // current B half (held across adjacent phases as in r8)

  // prologue: stage tile 0 (order A0,B0,A1,B1); need A0,B0 before ph0
  STG_A(0, 0, 0); STG_B(0, 0, 0); STG_A(1, 0, 0); STG_B(1, 0, 0);
  WVM(4);
  BARX;

#pragma unroll 2
  for (int t = 0; t < 16; ++t) {
    const int sl = t & 1, sn = sl ^ 1;
    const bool pf = (t < 15);
    // ---- phase 0: quadrant (0,0)
    RD_A(0, aF0); RD_B(0);
    if (pf) STG_A(0, sn, t + 1);
    BARX; WLG;
    __builtin_amdgcn_s_setprio(1); MQ(0, 0, aF0); __builtin_amdgcn_s_setprio(0);
    if (pf) { WVM(4); } else { WVM(2); }
    BARX;
    // ---- phase 1: quadrant (1,0)
    RD_A(1, aF1);
    if (pf) STG_B(0, sn, t + 1);
    BARX; WLG;
    __builtin_amdgcn_s_setprio(1); MQ(1, 0, aF1); __builtin_amdgcn_s_setprio(0);
    if (pf) { WVM(4); } else { WVM(0); }
    BARX;
    // ---- phase 2: quadrant (1,1)
    RD_B(1);
    if (pf) STG_A(1, sn, t + 1);
    BARX; WLG;
    __builtin_amdgcn_s_setprio(1); MQ(1, 1, aF1); __builtin_amdgcn_s_setprio(0);
    BARX;
    // ---- phase 3: quadrant (0,1) — aF0 + bF both held, NO LDS read
    if (pf) STG_B(1, sn, t + 1);
    BARX; WLG;
    __builtin_amdgcn_s_setprio(1); MQ(0, 1, aF0); __builtin_amdgcn_s_setprio(0);
    if (pf) WVM(4);
    BARX;
  }
}

// --------- fused QKV GEMM + repack:  qkv = x @ Wqkv^T, scatter to q/kT/vT --
// A = x_bf [16384][1024], W = wqkv_bf [3072][1024]. 256x256 tile, 8-phase.
// Grid: 768 blocks; xcd = lin&7 owns m-tiles [xcd*8, xcd*8+8) x all 12 n.
__global__ __launch_bounds__(512) void gemm_qkv(
    const ushort_t* __restrict__ A, const ushort_t* __restrict__ W,
    ushort_t* __restrict__ q, ushort_t* __restrict__ kT, ushort_t* __restrict__ vT) {
  __shared__ __align__(16) char smem[131072];
  const int lin = blockIdx.x;
  const int xcd = lin & 7, rr_ = lin >> 3;          // rr_ 0..95
  const int mt = xcd * 8 + (rr_ & 7);               // 0..63 (m-fastest in chunk)
  const int nt = rr_ >> 3;                          // 0..11
  const long long m0 = (long long)mt * 256;
  const long long n0 = (long long)nt * 256;

  f32x4 acc[8][4];
  pipe256(A, W, m0, n0, smem, acc);

  const int tid = threadIdx.x, lane = tid & 63, w = tid >> 6;
  const int l15 = lane & 15, quad = lane >> 4;
  const int wm = w >> 2, wn = w & 3;
  const int b     = (int)(m0 >> 12);
  const int nrow0 = (int)(m0 & 4095);
  const int s     = (int)(n0 >> 10);          // 0:q 1:k 2:v
  const int ncol0 = (int)(n0 & 1023);
  const int h0    = ncol0 >> 6;

  if (s == 0) {
#pragma unroll
    for (int mh = 0; mh < 2; mh++)
#pragma unroll
      for (int i = 0; i < 4; i++)
#pragma unroll
        for (int nh = 0; nh < 2; nh++)
#pragma unroll
          for (int j = 0; j < 2; j++) {
            int cx = ncol0 + nh * 128 + wn * 32 + j * 16;
            int h  = cx >> 6;
            int dd = (cx & 63) + l15;
            long long z = (long long)b * 16 + h;
            int nb = nrow0 + mh * 128 + wm * 64 + i * 16 + quad * 4;
#pragma unroll
            for (int r = 0; r < 4; r++)
              q[z * 262144 + (long long)(nb + r) * 64 + dd] = f2bf(acc[mh * 4 + i][nh * 2 + j][r]);
          }
  } else {
    // transpose through LDS in two 128-row passes: T[col 256][row 128 +pad]
    ushort_t (*T)[136] = (ushort_t(*)[136])smem;   // 256*136*2 = 69,632 B
    ushort_t* KV = (s == 1) ? kT : vT;
#pragma unroll
    for (int p = 0; p < 2; p++) {
      __syncthreads();
#pragma unroll
      for (int i = 0; i < 4; i++)
#pragma unroll
        for (int nh = 0; nh < 2; nh++)
#pragma unroll
          for (int j = 0; j < 2; j++) {
            int c = nh * 128 + wn * 32 + j * 16 + l15;
            int t = wm * 64 + i * 16 + quad * 4;
            ushort4_t o = {f2bf(acc[p * 4 + i][nh * 2 + j][0]), f2bf(acc[p * 4 + i][nh * 2 + j][1]),
                           f2bf(acc[p * 4 + i][nh * 2 + j][2]), f2bf(acc[p * 4 + i][nh * 2 + j][3])};
            *(ushort4_t*)(&T[c][t]) = o;
          }
      __syncthreads();
#pragma unroll
      for (int it = 0; it < 8; it++) {
        int ch = it * 512 + tid;
        int cl = ch >> 4, tc = (ch & 15) * 8;
        ushort8 v = *(const ushort8*)(&T[cl][tc]);
        int h = h0 + (cl >> 6), dd = cl & 63;
        long long z = (long long)b * 16 + h;
        *(ushort8*)(KV + z * 262144 + (long long)dd * 4096 + (nrow0 + p * 128 + tc)) = v;
      }
    }
  }
}

// ---- fused landmark partials: pK/pV[(z*4+s)*16384 + k*64 + d] -------------
//   = sum_{n in split s} E[h][k][n] * {kT,vT}[z][d][n]
// r15: kt merged into the block. 256 blocks (z,s), 512 thr / 8 waves, all
// 256 landmark rows per block -> kT/vT staged 1x instead of 4x.
// 3-buffer prefetch-distance-2 pipeline (9 loads in flight, vmcnt(6)) to
// cover HBM latency at 1 block/CU. Bank swizzle as r14 (64 B rows).
// Per buffer (24 KB = 12288 ushorts): E [0,8192) K [8192,10240) V [10240,12288).
#define LMSTG(b_, t_) do { \
    ushort_t* bb = smem + (b_) * 12288; \
    gload_lds16(gE0 + (t_) * 32, bb + w * 1024); \
    gload_lds16(gE1 + (t_) * 32, bb + w * 1024 + 512); \
    gload_lds16(gKV + (t_) * 32, bb + 8192 + w * 512); \
  } while (0)

#define LMCMP(b_) do { \
    const ushort_t* bb = smem + (b_) * 12288; \
    bf16x8 ef0 = *(const bf16x8*)(bb + (w * 32 + l15) * 32 + ((quad ^ swz) * 8)); \
    bf16x8 ef1 = *(const bf16x8*)(bb + (w * 32 + 16 + l15) * 32 + ((quad ^ swz) * 8)); \
    _Pragma("unroll") for (int j_ = 0; j_ < 4; j_++) { \
      bf16x8 kf = *(const bf16x8*)(bb + 8192 + (j_ * 16 + l15) * 32 + ((quad ^ swz) * 8)); \
      aK[0][j_] = __builtin_amdgcn_mfma_f32_16x16x32_bf16(ef0, kf, aK[0][j_], 0, 0, 0); \
      aK[1][j_] = __builtin_amdgcn_mfma_f32_16x16x32_bf16(ef1, kf, aK[1][j_], 0, 0, 0); \
      bf16x8 vf = *(const bf16x8*)(bb + 10240 + (j_ * 16 + l15) * 32 + ((quad ^ swz) * 8)); \
      aV[0][j_] = __builtin_amdgcn_mfma_f32_16x16x32_bf16(ef0, vf, aV[0][j_], 0, 0, 0); \
      aV[1][j_] = __builtin_amdgcn_mfma_f32_16x16x32_bf16(ef1, vf, aV[1][j_], 0, 0, 0); \
    } } while (0)

__global__ __launch_bounds__(512) void lm_gemm(
    const ushort_t* __restrict__ E, const ushort_t* __restrict__ kT,
    const ushort_t* __restrict__ vT, float* __restrict__ pK, float* __restrict__ pV) {
  __shared__ __align__(16) ushort_t smem[36864];  // 3 buffers x 24 KB = 72 KB
  const int tid = threadIdx.x, lane = tid & 63, w = tid >> 6;   // w 0..7
  const int l15 = lane & 15, quad = lane >> 4;
  // ---- XCD-chunked decode (bijective on 0..255) ----
  const int lin = blockIdx.x;
  const int xcd = lin & 7, idx = lin >> 3;   // idx 0..31
  const int h   = xcd + 8 * (idx >> 4);      // xcd owns h in {xcd, xcd+8}
  const int rem = idx & 15;
  const int zi  = rem & 3;                   // fastest: E slice L2-reuse
  const int s   = rem >> 2;                  // 0..3 split over n
  const int z   = zi * 16 + h;               // z & 15 == h
  const int lr = lane >> 2;
  // pre-swizzled source column: chunk (lane&3) ^ ((lr>>1)&3), in 8-ushort units
  const int lc = ((lane & 3) ^ ((lr >> 1) & 3)) * 8;
  const int swz = (l15 >> 1) & 3;  // read-side swizzle (row & 15 == l15)

  // wave w stages E rows [w*32, w*32+32) (2 calls) and K rows w*16 (w<4)
  // or V rows (w-4)*16 (w>=4); LDS dest 8192 + w*512 covers both halves.
  const ushort_t* gE0 = E + ((long long)h * 256 + w * 32 + lr) * 4096 + s * 1024 + lc;
  const ushort_t* gE1 = gE0 + 16 * 4096;
  const ushort_t* gKV = (w < 4)
      ? kT + ((long long)z * 64 + w * 16 + lr) * 4096 + s * 1024 + lc
      : vT + ((long long)z * 64 + (w - 4) * 16 + lr) * 4096 + s * 1024 + lc;

  const f32x4 zz = {0.f, 0.f, 0.f, 0.f};
  f32x4 aK[2][4], aV[2][4];
#pragma unroll
  for (int f = 0; f < 2; f++)
#pragma unroll
    for (int j = 0; j < 4; j++) { aK[f][j] = zz; aV[f][j] = zz; }

  // 3-buffer, prefetch-distance-2 pipeline over 32 panels of 32 n-cols
  LMSTG(0, 0); LMSTG(1, 1);          // 6 outstanding / wave
#pragma unroll 3
  for (int t = 0; t < 30; ++t) {
    LMSTG((t + 2) % 3, t + 2);       // 9 outstanding
    WVM(6);                           // panel t's 3 landed; t+1,t+2 in flight
    BARX;
    LMCMP(t % 3);
    BARX;                             // all reads done before buffer reuse
  }
  WVM(3); BARX; LMCMP(0);  BARX;      // panel 30 (buf 0)
  WVM(0); BARX; LMCMP(1);             // panel 31 (buf 1)

  float* oK = pK + (long long)(z * 4 + s) * 16384;
  float* oV = pV + (long long)(z * 4 + s) * 16384;
#pragma unroll
  for (int f = 0; f < 2; f++)
#pragma unroll
    for (int j = 0; j < 4; j++)
#pragma unroll
      for (int r = 0; r < 4; r++) {
        int row = w * 32 + f * 16 + quad * 4 + r, col = j * 16 + l15;
        oK[row * 64 + col] = aK[f][j][r];
        oV[row * 64 + col] = aV[f][j][r];
      }
}

// ---- reduce 4 splits -> klm[z][k][d] bf16 and vlmT[z][d][k] bf16 ----------
__global__ __launch_bounds__(256) void lm_reduce(
    const float* __restrict__ pK, const float* __restrict__ pV,
    ushort_t* __restrict__ klm, ushort_t* __restrict__ vlmT) {
  __shared__ float Tv[64][68];
  const int tid = threadIdx.x;
  const int kt = blockIdx.x;   // 0..3
  const int z  = blockIdx.y;   // 0..63
  const long long base = (long long)z * 4 * 16384 + kt * 64 * 64;
  const int row = tid >> 2, c0 = (tid & 3) * 16;

  float sk[16];
#pragma unroll
  for (int g = 0; g < 4; g++) {
    f32x4 a = {0.f, 0.f, 0.f, 0.f};
#pragma unroll
    for (int s = 0; s < 4; s++)
      a += *(const f32x4*)(pK + base + (long long)s * 16384 + row * 64 + c0 + g * 4);
    sk[g * 4 + 0] = a[0]; sk[g * 4 + 1] = a[1]; sk[g * 4 + 2] = a[2]; sk[g * 4 + 3] = a[3];
  }
  {
    ushort_t* dst = klm + ((long long)z * 256 + kt * 64 + row) * 64 + c0;
    ushort8 o0, o1;
#pragma unroll
    for (int i = 0; i < 8; i++) { o0[i] = f2bf(sk[i]); o1[i] = f2bf(sk[8 + i]); }
    *(ushort8*)(dst) = o0;
    *(ushort8*)(dst + 8) = o1;
  }

#pragma unroll
  for (int g = 0; g < 4; g++) {
    f32x4 a = {0.f, 0.f, 0.f, 0.f};
#pragma unroll
    for (int s = 0; s < 4; s++)
      a += *(const f32x4*)(pV + base + (long long)s * 16384 + row * 64 + c0 + g * 4);
    *(f32x4*)(&Tv[row][c0 + g * 4]) = a;
  }
  __syncthreads();
  {
    ushort8 o0, o1;
#pragma unroll
    for (int i = 0; i < 8; i++) {
      o0[i] = f2bf(Tv[c0 + i][row]);
      o1[i] = f2bf(Tv[c0 + 8 + i][row]);
    }
    ushort_t* dst = vlmT + ((long long)z * 64 + row) * 256 + kt * 64 + c0;
    *(ushort8*)(dst) = o0;
    *(ushort8*)(dst + 8) = o1;
  }
}

// -------- fused flash-style: O = softmax(q@k_lm^T/8) @ v_lm  ---------------
__global__ __launch_bounds__(256) void attn_fused(
    const ushort_t* __restrict__ Q, const ushort_t* __restrict__ Klm,
    const ushort_t* __restrict__ VlmT, ushort_t* __restrict__ O) {
  __shared__ __align__(16) ushort_t smem[16896];          // 33,792 B
  ushort_t (*As)[40]  = (ushort_t(*)[40])smem;            // [64][40]
  ushort_t (*Bs)[40]  = (ushort_t(*)[40])(smem + 2560);   // [256][40]
  ushort_t (*P)[264]  = (ushort_t(*)[264])smem;           // [64][264] (aliases)
  const int tid = threadIdx.x, lane = tid & 63, w = tid >> 6;
  const int l15 = lane & 15, quad = lane >> 4;
  const int z = blockIdx.z;
  const long long m0 = (long long)blockIdx.x * 64;
  const ushort_t* Qb = Q + (long long)z * 262144;
  const ushort_t* Kb = Klm + (long long)z * 16384;
  const ushort_t* Vb = VlmT + (long long)z * 16384;

  const f32x4 zz = {0.f, 0.f, 0.f, 0.f};
  f32x4 acc[16];
#pragma unroll
  for (int j = 0; j < 16; j++) acc[j] = zz;

  const int sr = tid >> 2, sc = (tid & 3) * 8;

  // ---- phase 1: scores S[64][256] in registers ----
  for (int kt = 0; kt < 2; kt++) {
    const int k0 = kt * 32;
    ushort8 av = *(const ushort8*)(Qb + (m0 + sr) * 64 + k0 + sc);
    ushort8 bv[4];
#pragma unroll
    for (int r = 0; r < 4; r++) {
      int c = r * 256 + tid;
      bv[r] = *(const ushort8*)(Kb + (c >> 2) * 64 + k0 + (c & 3) * 8);
    }
    __syncthreads();
    *(ushort8*)(&As[sr][sc]) = av;
#pragma unroll
    for (int r = 0; r < 4; r++) {
      int c = r * 256 + tid;
      *(ushort8*)(&Bs[c >> 2][(c & 3) * 8]) = bv[r];
    }
    __syncthreads();
    bf16x8 af = *(const bf16x8*)(&As[w * 16 + l15][quad * 8]);
#pragma unroll
    for (int j = 0; j < 16; j++) {
      bf16x8 bfj = *(const bf16x8*)(&Bs[j * 16 + l15][quad * 8]);
      acc[j] = __builtin_amdgcn_mfma_f32_16x16x32_bf16(af, bfj, acc[j], 0, 0, 0);
    }
  }

  // ---- phase 2: softmax over 256 landmarks, P -> LDS (D-layout -> A-layout)
  __syncthreads();
#pragma unroll
  for (int r = 0; r < 4; r++) {
    float x[16];
    float vmax = -1e30f;
#pragma unroll
    for (int j = 0; j < 16; j++) { x[j] = acc[j][r] * 0.125f; vmax = fmaxf(vmax, x[j]); }
#pragma unroll
    for (int m = 1; m < 16; m <<= 1) vmax = fmaxf(vmax, __shfl_xor(vmax, m, 64));
    float s = 0.f;
#pragma unroll
    for (int j = 0; j < 16; j++) { x[j] = __expf(x[j] - vmax); s += x[j]; }
#pragma unroll
    for (int m = 1; m < 16; m <<= 1) s += __shfl_xor(s, m, 64);
    float inv = 1.0f / s;
    int row = w * 16 + quad * 4 + r;
#pragma unroll
    for (int j = 0; j < 16; j++)
      P[row][j * 16 + l15] = f2bf(x[j] * inv);
  }
  __syncthreads();

  // ---- phase 3: O[64][64] = P @ VlmT^T ----
  f32x4 o_acc[4];
#pragma unroll
  for (int j = 0; j < 4; j++) o_acc[j] = zz;
#pragma unroll
  for (int kc = 0; kc < 8; kc++) {
    bf16x8 pf = *(const bf16x8*)(&P[w * 16 + l15][kc * 32 + quad * 8]);
#pragma unroll
    for (int j = 0; j < 4; j++) {
      bf16x8 vf = *(const bf16x8*)(Vb + (j * 16 + l15) * 256 + kc * 32 + quad * 8);
      o_acc[j] = __builtin_amdgcn_mfma_f32_16x16x32_bf16(pf, vf, o_acc[j], 0, 0, 0);
    }
  }

#pragma unroll
  for (int j = 0; j < 4; j++)
#pragma unroll
    for (int r = 0; r < 4; r++) {
      int row = w * 16 + quad * 4 + r;
      int col = j * 16 + l15;
      O[(long long)z * 262144 + (m0 + row) * 64 + col] = f2bf(o_acc[j][r]);
    }
}

// ------------------- 256x256 tile NT GEMM, f32 out (+bias) -----------------
// A [16384][1024] bf16, B [1024][1024] bf16, C [16384][1024] f32.
// Grid: 256 blocks; xcd = lin&7 owns m-tiles [xcd*8, xcd*8+8) x all 4 n.
__global__ __launch_bounds__(512) void gemm_nt_256(
    const ushort_t* __restrict__ A, const ushort_t* __restrict__ B,
    float* __restrict__ C, const float* __restrict__ bias) {
  __shared__ __align__(16) char smem[131072];
  const int lin = blockIdx.x;
  const int xcd = lin & 7, rr_ = lin >> 3;          // rr_ 0..31
  const int mt = xcd * 8 + (rr_ & 7);               // 0..63
  const int nt = rr_ >> 3;                          // 0..3
  const long long m0 = (long long)mt * 256;
  const long long n0 = (long long)nt * 256;

  f32x4 acc[8][4];
  pipe256(A, B, m0, n0, smem, acc);

  const int tid = threadIdx.x, lane = tid & 63, w = tid >> 6;
  const int l15 = lane & 15, quad = lane >> 4;
  const int wm = w >> 2, wn = w & 3;

#pragma unroll
  for (int mh = 0; mh < 2; mh++)
#pragma unroll
    for (int i = 0; i < 4; i++)
#pragma unroll
      for (int nh = 0; nh < 2; nh++)
#pragma unroll
        for (int j = 0; j < 2; j++) {
          long long row = m0 + mh * 128 + wm * 64 + i * 16 + quad * 4;
          long long col = n0 + nh * 128 + wn * 32 + j * 16 + l15;
          float bv = bias[col];
#pragma unroll
          for (int r = 0; r < 4; r++)
            C[(row + r) * 1024 + col] = acc[mh * 4 + i][nh * 2 + j][r] + bv;
        }
}

// ---------------------------------------------------------------------------
extern "C" void kernel_launch(void* const* d_in, const int* in_sizes, int n_in,
                              void* d_out, int out_size, void* d_ws, size_t ws_size,
                              hipStream_t stream) {
  const float* x     = (const float*)d_in[0];
  const float* Wqkv  = (const float*)d_in[1];
  const float* E     = (const float*)d_in[2];
  const float* Wproj = (const float*)d_in[3];
  const float* bproj = (const float*)d_in[4];
  float* out = (float*)d_out;

  char* ws = (char*)d_ws;
  ushort_t* x_bf     = (ushort_t*)(ws + 0);            // 32 MB; later pK/pV, then attn O
  float*    pK       = (float*)   (ws + 0);            // 16 MB (after gemm_qkv)
  float*    pV       = (float*)   (ws + 16777216);     // 16 MB
  ushort_t* wqkv_bf  = (ushort_t*)(ws + 33554432);     //  6 MB
  ushort_t* e_bf     = (ushort_t*)(ws + 39845888);     // 32 MB
  ushort_t* wproj_bf = (ushort_t*)(ws + 73400320);     //  2 MB
  ushort_t* q_bf     = (ushort_t*)(ws + 75497472);     // 32 MB
  ushort_t* kT       = (ushort_t*)(ws + 109051904);    // 32 MB
  ushort_t* vT       = (ushort_t*)(ws + 142606336);    // 32 MB
  ushort_t* klm      = (ushort_t*)(ws + 176160768);    //  2 MB
  ushort_t* vlmT     = (ushort_t*)(ws + 178257920);    //  2 MB
  // total: 180,355,072 bytes

  // 1) fused f32 -> bf16 converts (one dispatch)
  cvt_all<<<36864, 256, 0, stream>>>(x, x_bf, Wqkv, wqkv_bf, E, e_bf, Wproj, wproj_bf);

  // 2) fused QKV GEMM + repack -> q(n,d), kT(d,n), vT(d,n) bf16  [8-phase 256^2]
  gemm_qkv<<<768, 512, 0, stream>>>(x_bf, wqkv_bf, q_bf, kT, vT);

  // 3) landmark partials: kt-merged, 256 blocks x 512 thr, depth-2 prefetch
  lm_gemm<<<256, 512, 0, stream>>>(e_bf, kT, vT, pK, pV);

  // 4) reduce splits -> klm[z][k][d], vlmT[z][d][k]
  lm_reduce<<<dim3(4, 64), 256, 0, stream>>>(pK, pV, klm, vlmT);

  // 5) fused scores+softmax+PV -> attn_out (B,H,N,d) contiguous
  attn_fused<<<dim3(64, 1, 64), 256, 0, stream>>>(q_bf, klm, vlmT, x_bf);

  // 6) out = attn_out @ Wproj^T + bproj  [16384 x 1024] f32  [8-phase 256^2]
  gemm_nt_256<<<256, 512, 0, stream>>>(x_bf, wproj_bf, out, bproj);
}

// Round 11
// 431.692 us; speedup vs baseline: 1.0066x; 1.0066x over previous
//
#include <hip/hip_runtime.h>

// ---------------------------------------------------------------------------
// LinformerAttention on MI355X (gfx950) — round 18 (= round 16/17 resubmitted;
// r16 and r17 benches both lost to GPUAcquisitionTimeout, no data).
// B=4, N=4096, C=1024, H=16, K_LM=256, d=64.
// r15 post-mortem (fast-clock compare vs r13): lm kt-merge REGRESSED ~9 us
// (1 block/CU: depth-2 prefetch < HBM latency; 8-wave barriers). Closed.
// -> lm_gemm reverted to r14: 1024 blocks (4/CU TLP), 32-col panels,
//    double-buffer, counted vmcnt(3), XCD-chunked remap (r12).
// Live experiment: attn_fused XCD-chunked block remap (T1).
//   Old grid (x=64,z=64), x fastest: 64 blocks sharing z (same 64 KB
//   Klm+VlmT) round-robin across 8 XCDs -> cross-XCD L2 misses.
//   New: 1D 4096; xcd = lin&7 owns z in [xcd*8, xcd*8+8), m-tile fastest
//   -> one z's KV resident in its XCD L2 across its 64 consecutive blocks.
// Everything else identical to the r13/r14-verified code.
// ---------------------------------------------------------------------------

typedef unsigned short ushort_t;
typedef float f32x4 __attribute__((ext_vector_type(4)));
typedef __bf16 bf16x8 __attribute__((ext_vector_type(8)));
typedef unsigned short ushort8 __attribute__((ext_vector_type(8)));
typedef unsigned short ushort4_t __attribute__((ext_vector_type(4)));

__device__ inline ushort_t f2bf(float f) {
  unsigned int u = __float_as_uint(f);
  u += 0x7fff + ((u >> 16) & 1);   // RNE
  return (ushort_t)(u >> 16);
}

// async global -> LDS, 16 B per lane. LDS dest is wave-uniform base + lane*16.
__device__ inline void gload_lds16(const ushort_t* g, ushort_t* l) {
  __builtin_amdgcn_global_load_lds(
      (const __attribute__((address_space(1))) void*)g,
      (__attribute__((address_space(3))) void*)l, 16, 0, 0);
}

// --------------- fused f32 -> bf16 convert of all four inputs --------------
__global__ __launch_bounds__(256) void cvt_all(
    const float* __restrict__ x,  ushort_t* __restrict__ xo,
    const float* __restrict__ w1, ushort_t* __restrict__ w1o,
    const float* __restrict__ e,  ushort_t* __restrict__ eo,
    const float* __restrict__ w2, ushort_t* __restrict__ w2o) {
  // float4 chunk counts: x 4194304 | Wqkv 786432 | E 4194304 | Wproj 262144
  int i = blockIdx.x * blockDim.x + threadIdx.x;
  const float* in; ushort_t* out; int idx;
  if (i < 4194304)               { in = x;  out = xo;  idx = i; }
  else if (i < 4980736)          { in = w1; out = w1o; idx = i - 4194304; }
  else if (i < 9175040)          { in = e;  out = eo;  idx = i - 4980736; }
  else                           { in = w2; out = w2o; idx = i - 9175040; }
  float4 v = ((const float4*)in)[idx];
  ushort4_t o;
  o.x = f2bf(v.x); o.y = f2bf(v.y); o.z = f2bf(v.z); o.w = f2bf(v.w);
  ((ushort4_t*)out)[idx] = o;
}

// ===========================================================================
// 256x256 8-phase pipelined GEMM core (C = A @ B^T), K = 1024, bf16 in.
// (r13 schedule, verified: A0 held in regs, 24 ds_read_b128/wave/tile floor.)
// ===========================================================================

#define BARX __builtin_amdgcn_s_barrier()
#define WVM(n) do { asm volatile("s_waitcnt vmcnt(" #n ")" ::: "memory"); \
                    __builtin_amdgcn_sched_barrier(0); } while (0)
#define WLG  do { asm volatile("s_waitcnt lgkmcnt(0)" ::: "memory"); \
                  __builtin_amdgcn_sched_barrier(0); } while (0)

#define STG_A(h, slot, tt) do { \
    gload_lds16(sA[h][0] + (tt) * 64, (ushort_t*)(smem + (slot) * 32768 + (h) * 16384 + (w * 2 + 0) * 1024)); \
    gload_lds16(sA[h][1] + (tt) * 64, (ushort_t*)(smem + (slot) * 32768 + (h) * 16384 + (w * 2 + 1) * 1024)); \
  } while (0)
#define STG_B(h, slot, tt) do { \
    gload_lds16(sB[h][0] + (tt) * 64, (ushort_t*)(smem + 65536 + (slot) * 32768 + (h) * 16384 + (w * 2 + 0) * 1024)); \
    gload_lds16(sB[h][1] + (tt) * 64, (ushort_t*)(smem + 65536 + (slot) * 32768 + (h) * 16384 + (w * 2 + 1) * 1024)); \
  } while (0)

#define RD_A(mh, AF) do { \
    const char* ba_ = smem + sl * 32768 + ((mh) * 128 + wm * 64 + l15) * 128; \
    _Pragma("unroll") for (int i_ = 0; i_ < 4; i_++) { \
      AF[i_][0] = *(const bf16x8*)(ba_ + i_ * 2048 + cs0); \
      AF[i_][1] = *(const bf16x8*)(ba_ + i_ * 2048 + cs1); } \
  } while (0)
#define RD_B(nh) do { \
    const char* bb_ = smem + 65536 + sl * 32768 + ((nh) * 128 + wn * 32 + l15) * 128; \
    _Pragma("unroll") for (int j_ = 0; j_ < 2; j_++) { \
      bF[j_][0] = *(const bf16x8*)(bb_ + j_ * 2048 + cs0); \
      bF[j_][1] = *(const bf16x8*)(bb_ + j_ * 2048 + cs1); } \
  } while (0)

#define MQ(mh, nh, AF) do { \
    _Pragma("unroll") for (int i_ = 0; i_ < 4; i_++) \
    _Pragma("unroll") for (int j_ = 0; j_ < 2; j_++) { \
      acc[(mh) * 4 + i_][(nh) * 2 + j_] = __builtin_amdgcn_mfma_f32_16x16x32_bf16( \
          AF[i_][0], bF[j_][0], acc[(mh) * 4 + i_][(nh) * 2 + j_], 0, 0, 0); \
      acc[(mh) * 4 + i_][(nh) * 2 + j_] = __builtin_amdgcn_mfma_f32_16x16x32_bf16( \
          AF[i_][1], bF[j_][1], acc[(mh) * 4 + i_][(nh) * 2 + j_], 0, 0, 0); } \
  } while (0)

__device__ __attribute__((always_inline)) inline void pipe256(
    const ushort_t* __restrict__ Ag, const ushort_t* __restrict__ Bg,
    long long m0, long long n0, char* smem, f32x4 acc[8][4]) {
  const int tid = threadIdx.x, lane = tid & 63, w = tid >> 6;
  const int l15 = lane & 15, quad = lane >> 4;
  const int wm = w >> 2, wn = w & 3;
  const int sw = l15 & 7;
  const int K = 1024;
  // swizzled ds_read byte offsets within a 128 B row, for k-step 0 / 1
  const int cs0 = ((0 * 4 + quad) ^ sw) << 4;
  const int cs1 = ((1 * 4 + quad) ^ sw) << 4;
  // staging source: lane L of chunk c=(w*2+q) covers LDS row c*8+(L>>3),
  // slot L&7 -> global k-chunk (L&7)^((L>>3)&7)  (row&7 == (L>>3)&7).
  const int lr8 = lane >> 3;
  const int sdat = ((lane & 7) ^ lr8) * 8;
  const ushort_t* sA[2][2];
  const ushort_t* sB[2][2];
#pragma unroll
  for (int h = 0; h < 2; h++)
#pragma unroll
    for (int q = 0; q < 2; q++) {
      sA[h][q] = Ag + (m0 + h * 128 + (w * 2 + q) * 8 + lr8) * K + sdat;
      sB[h][q] = Bg + (n0 + h * 128 + (w * 2 + q) * 8 + lr8) * K + sdat;
    }

  const f32x4 zz = {0.f, 0.f, 0.f, 0.f};
#pragma unroll
  for (int i = 0; i < 8; i++)
#pragma unroll
    for (int j = 0; j < 4; j++) acc[i][j] = zz;

  bf16x8 aF0[4][2];  // A half 0 — read in ph0, HELD through ph3
  bf16x8 aF1[4][2];  // A half 1 — read in ph1, used ph1/ph2
  bf16x8 bF[2][2];   // current B half (held across adjacent phases as in r8)

  // prologue: stage tile 0 (order A0,B0,A1,B1); need A0,B0 before ph0
  STG_A(0, 0, 0); STG_B(0, 0, 0); STG_A(1, 0, 0); STG_B(1, 0, 0);
  WVM(4);
  BARX;

#pragma unroll 2
  for (int t = 0; t < 16; ++t) {
    const int sl = t & 1, sn = sl ^ 1;
    const bool pf = (t < 15);
    // ---- phase 0: quadrant (0,0)
    RD_A(0, aF0); RD_B(0);
    if (pf) STG_A(0, sn, t + 1);
    BARX; WLG;
    __builtin_amdgcn_s_setprio(1); MQ(0, 0, aF0); __builtin_amdgcn_s_setprio(0);
    if (pf) { WVM(4); } else { WVM(2); }
    BARX;
    // ---- phase 1: quadrant (1,0)
    RD_A(1, aF1);
    if (pf) STG_B(0, sn, t + 1);
    BARX; WLG;
    __builtin_amdgcn_s_setprio(1); MQ(1, 0, aF1); __builtin_amdgcn_s_setprio(0);
    if (pf) { WVM(4); } else { WVM(0); }
    BARX;
    // ---- phase 2: quadrant (1,1)
    RD_B(1);
    if (pf) STG_A(1, sn, t + 1);
    BARX; WLG;
    __builtin_amdgcn_s_setprio(1); MQ(1, 1, aF1); __builtin_amdgcn_s_setprio(0);
    BARX;
    // ---- phase 3: quadrant (0,1) — aF0 + bF both held, NO LDS read
    if (pf) STG_B(1, sn, t + 1);
    BARX; WLG;
    __builtin_amdgcn_s_setprio(1); MQ(0, 1, aF0); __builtin_amdgcn_s_setprio(0);
    if (pf) WVM(4);
    BARX;
  }
}

// --------- fused QKV GEMM + repack:  qkv = x @ Wqkv^T, scatter to q/kT/vT --
// A = x_bf [16384][1024], W = wqkv_bf [3072][1024]. 256x256 tile, 8-phase.
// Grid: 768 blocks; xcd = lin&7 owns m-tiles [xcd*8, xcd*8+8) x all 12 n.
__global__ __launch_bounds__(512) void gemm_qkv(
    const ushort_t* __restrict__ A, const ushort_t* __restrict__ W,
    ushort_t* __restrict__ q, ushort_t* __restrict__ kT, ushort_t* __restrict__ vT) {
  __shared__ __align__(16) char smem[131072];
  const int lin = blockIdx.x;
  const int xcd = lin & 7, rr_ = lin >> 3;          // rr_ 0..95
  const int mt = xcd * 8 + (rr_ & 7);               // 0..63 (m-fastest in chunk)
  const int nt = rr_ >> 3;                          // 0..11
  const long long m0 = (long long)mt * 256;
  const long long n0 = (long long)nt * 256;

  f32x4 acc[8][4];
  pipe256(A, W, m0, n0, smem, acc);

  const int tid = threadIdx.x, lane = tid & 63, w = tid >> 6;
  const int l15 = lane & 15, quad = lane >> 4;
  const int wm = w >> 2, wn = w & 3;
  const int b     = (int)(m0 >> 12);
  const int nrow0 = (int)(m0 & 4095);
  const int s     = (int)(n0 >> 10);          // 0:q 1:k 2:v
  const int ncol0 = (int)(n0 & 1023);
  const int h0    = ncol0 >> 6;

  if (s == 0) {
#pragma unroll
    for (int mh = 0; mh < 2; mh++)
#pragma unroll
      for (int i = 0; i < 4; i++)
#pragma unroll
        for (int nh = 0; nh < 2; nh++)
#pragma unroll
          for (int j = 0; j < 2; j++) {
            int cx = ncol0 + nh * 128 + wn * 32 + j * 16;
            int h  = cx >> 6;
            int dd = (cx & 63) + l15;
            long long z = (long long)b * 16 + h;
            int nb = nrow0 + mh * 128 + wm * 64 + i * 16 + quad * 4;
#pragma unroll
            for (int r = 0; r < 4; r++)
              q[z * 262144 + (long long)(nb + r) * 64 + dd] = f2bf(acc[mh * 4 + i][nh * 2 + j][r]);
          }
  } else {
    // transpose through LDS in two 128-row passes: T[col 256][row 128 +pad]
    ushort_t (*T)[136] = (ushort_t(*)[136])smem;   // 256*136*2 = 69,632 B
    ushort_t* KV = (s == 1) ? kT : vT;
#pragma unroll
    for (int p = 0; p < 2; p++) {
      __syncthreads();
#pragma unroll
      for (int i = 0; i < 4; i++)
#pragma unroll
        for (int nh = 0; nh < 2; nh++)
#pragma unroll
          for (int j = 0; j < 2; j++) {
            int c = nh * 128 + wn * 32 + j * 16 + l15;
            int t = wm * 64 + i * 16 + quad * 4;
            ushort4_t o = {f2bf(acc[p * 4 + i][nh * 2 + j][0]), f2bf(acc[p * 4 + i][nh * 2 + j][1]),
                           f2bf(acc[p * 4 + i][nh * 2 + j][2]), f2bf(acc[p * 4 + i][nh * 2 + j][3])};
            *(ushort4_t*)(&T[c][t]) = o;
          }
      __syncthreads();
#pragma unroll
      for (int it = 0; it < 8; it++) {
        int ch = it * 512 + tid;
        int cl = ch >> 4, tc = (ch & 15) * 8;
        ushort8 v = *(const ushort8*)(&T[cl][tc]);
        int h = h0 + (cl >> 6), dd = cl & 63;
        long long z = (long long)b * 16 + h;
        *(ushort8*)(KV + z * 262144 + (long long)dd * 4096 + (nrow0 + p * 128 + tc)) = v;
      }
    }
  }
}

// ---- fused landmark partials: pK/pV[(z*4+s)*16384 + k*64 + d] -------------
//   = sum_{n in split s} E[h][k][n] * {kT,vT}[z][d][n]
// r14 version (best measured): XCD-chunked remap (r12) + counted-vmcnt
// double-buffer: 32-col panels, 2 buffers x 12 KB, 4 blocks/CU,
// stage panel t+1 (3 gloads) -> vmcnt(3) -> barrier -> compute(t) -> barrier.
#define LMSTG(b_, t_) do { \
    ushort_t* base_ = smem + (b_) * 6144; \
    gload_lds16(gE + (t_) * 32, base_ + 512 * w); \
    gload_lds16(gK + (t_) * 32, base_ + 2048 + 512 * w); \
    gload_lds16(gV + (t_) * 32, base_ + 4096 + 512 * w); \
  } while (0)

#define LMCMP(b_) do { \
    const ushort_t* base_ = smem + (b_) * 6144; \
    bf16x8 ef = *(const bf16x8*)(base_ + (w * 16 + l15) * 32 + ((quad ^ swz) * 8)); \
    _Pragma("unroll") for (int j_ = 0; j_ < 4; j_++) { \
      bf16x8 kf = *(const bf16x8*)(base_ + 2048 + (j_ * 16 + l15) * 32 + ((quad ^ swz) * 8)); \
      aK[j_] = __builtin_amdgcn_mfma_f32_16x16x32_bf16(ef, kf, aK[j_], 0, 0, 0); \
      bf16x8 vf = *(const bf16x8*)(base_ + 4096 + (j_ * 16 + l15) * 32 + ((quad ^ swz) * 8)); \
      aV[j_] = __builtin_amdgcn_mfma_f32_16x16x32_bf16(ef, vf, aV[j_], 0, 0, 0); \
    } } while (0)

__global__ __launch_bounds__(256) void lm_gemm(
    const ushort_t* __restrict__ E, const ushort_t* __restrict__ kT,
    const ushort_t* __restrict__ vT, float* __restrict__ pK, float* __restrict__ pV) {
  __shared__ __align__(16) ushort_t smem[12288];  // 2 buffers x [E 2048|K 2048|V 2048]
  const int tid = threadIdx.x, lane = tid & 63, w = tid >> 6;
  const int l15 = lane & 15, quad = lane >> 4;
  // ---- XCD-chunked decode (bijective on 0..1023) ----
  const int lin = blockIdx.x;
  const int xcd = lin & 7, idx = lin >> 3;   // idx 0..127
  const int h   = xcd + 8 * (idx >> 6);      // h 0..15: xcd owns {xcd, xcd+8}
  const int rem = idx & 63;
  const int kt  = rem & 3;                   // fastest: kT/vT slice L2-reuse
  const int zi  = (rem >> 2) & 3;            // next: E slice L2-reuse
  const int s   = rem >> 4;                  // 0..3
  const int z   = zi * 16 + h;               // z & 15 == h
  const int lr = lane >> 2;
  // pre-swizzled source column: chunk (lane&3) ^ ((lr>>1)&3), in 8-ushort units
  const int lc = ((lane & 3) ^ ((lr >> 1) & 3)) * 8;
  const int swz = (l15 >> 1) & 3;  // read-side swizzle (row & 15 == l15)

  const ushort_t* gE = E  + ((long long)h * 256 + kt * 64 + 16 * w + lr) * 4096 + s * 1024 + lc;
  const ushort_t* gK = kT + ((long long)z * 64 + 16 * w + lr) * 4096 + s * 1024 + lc;
  const ushort_t* gV = vT + ((long long)z * 64 + 16 * w + lr) * 4096 + s * 1024 + lc;

  const f32x4 zz = {0.f, 0.f, 0.f, 0.f};
  f32x4 aK[4], aV[4];
#pragma unroll
  for (int j = 0; j < 4; j++) { aK[j] = zz; aV[j] = zz; }

  // counted-vmcnt double-buffer pipeline over 32 panels of 32 n-cols
  LMSTG(0, 0);
#pragma unroll 2
  for (int t = 0; t < 31; ++t) {
    const int b = t & 1;
    LMSTG(b ^ 1, t + 1);   // issue next panel (3 loads) -> 6 outstanding
    WVM(3);                 // panel t's 3 landed; t+1 stays in flight
    BARX;
    LMCMP(b);
    BARX;                   // all reads of buffer b done before overwrite
  }
  WVM(0);
  BARX;
  LMCMP(1);                 // panel 31 (buffer 31&1 = 1)

  float* oK = pK + ((long long)(z * 4 + s) * 256 + kt * 64) * 64;
  float* oV = pV + ((long long)(z * 4 + s) * 256 + kt * 64) * 64;
#pragma unroll
  for (int j = 0; j < 4; j++)
#pragma unroll
    for (int r = 0; r < 4; r++) {
      int row = w * 16 + quad * 4 + r, col = j * 16 + l15;
      oK[row * 64 + col] = aK[j][r];
      oV[row * 64 + col] = aV[j][r];
    }
}

// ---- reduce 4 splits -> klm[z][k][d] bf16 and vlmT[z][d][k] bf16 ----------
__global__ __launch_bounds__(256) void lm_reduce(
    const float* __restrict__ pK, const float* __restrict__ pV,
    ushort_t* __restrict__ klm, ushort_t* __restrict__ vlmT) {
  __shared__ float Tv[64][68];
  const int tid = threadIdx.x;
  const int kt = blockIdx.x;   // 0..3
  const int z  = blockIdx.y;   // 0..63
  const long long base = (long long)z * 4 * 16384 + kt * 64 * 64;
  const int row = tid >> 2, c0 = (tid & 3) * 16;

  float sk[16];
#pragma unroll
  for (int g = 0; g < 4; g++) {
    f32x4 a = {0.f, 0.f, 0.f, 0.f};
#pragma unroll
    for (int s = 0; s < 4; s++)
      a += *(const f32x4*)(pK + base + (long long)s * 16384 + row * 64 + c0 + g * 4);
    sk[g * 4 + 0] = a[0]; sk[g * 4 + 1] = a[1]; sk[g * 4 + 2] = a[2]; sk[g * 4 + 3] = a[3];
  }
  {
    ushort_t* dst = klm + ((long long)z * 256 + kt * 64 + row) * 64 + c0;
    ushort8 o0, o1;
#pragma unroll
    for (int i = 0; i < 8; i++) { o0[i] = f2bf(sk[i]); o1[i] = f2bf(sk[8 + i]); }
    *(ushort8*)(dst) = o0;
    *(ushort8*)(dst + 8) = o1;
  }

#pragma unroll
  for (int g = 0; g < 4; g++) {
    f32x4 a = {0.f, 0.f, 0.f, 0.f};
#pragma unroll
    for (int s = 0; s < 4; s++)
      a += *(const f32x4*)(pV + base + (long long)s * 16384 + row * 64 + c0 + g * 4);
    *(f32x4*)(&Tv[row][c0 + g * 4]) = a;
  }
  __syncthreads();
  {
    ushort8 o0, o1;
#pragma unroll
    for (int i = 0; i < 8; i++) {
      o0[i] = f2bf(Tv[c0 + i][row]);
      o1[i] = f2bf(Tv[c0 + 8 + i][row]);
    }
    ushort_t* dst = vlmT + ((long long)z * 64 + row) * 256 + kt * 64 + c0;
    *(ushort8*)(dst) = o0;
    *(ushort8*)(dst + 8) = o1;
  }
}

// -------- fused flash-style: O = softmax(q@k_lm^T/8) @ v_lm  ---------------
// XCD-chunked 1D grid — xcd = lin&7 owns z in [xcd*8, xcd*8+8),
// m-tile fastest within a z so that z's 64 KB Klm+VlmT stays in its XCD L2.
__global__ __launch_bounds__(256) void attn_fused(
    const ushort_t* __restrict__ Q, const ushort_t* __restrict__ Klm,
    const ushort_t* __restrict__ VlmT, ushort_t* __restrict__ O) {
  __shared__ __align__(16) ushort_t smem[16896];          // 33,792 B
  ushort_t (*As)[40]  = (ushort_t(*)[40])smem;            // [64][40]
  ushort_t (*Bs)[40]  = (ushort_t(*)[40])(smem + 2560);   // [256][40]
  ushort_t (*P)[264]  = (ushort_t(*)[264])smem;           // [64][264] (aliases)
  const int tid = threadIdx.x, lane = tid & 63, w = tid >> 6;
  const int l15 = lane & 15, quad = lane >> 4;
  // ---- XCD-chunked decode (bijective on 0..4095) ----
  const int lin = blockIdx.x;
  const int xcd = lin & 7, idx = lin >> 3;  // idx 0..511
  const int z   = xcd * 8 + (idx >> 6);     // 8 z's per XCD
  const int mt  = idx & 63;                 // m-tile fastest
  const long long m0 = (long long)mt * 64;
  const ushort_t* Qb = Q + (long long)z * 262144;
  const ushort_t* Kb = Klm + (long long)z * 16384;
  const ushort_t* Vb = VlmT + (long long)z * 16384;

  const f32x4 zz = {0.f, 0.f, 0.f, 0.f};
  f32x4 acc[16];
#pragma unroll
  for (int j = 0; j < 16; j++) acc[j] = zz;

  const int sr = tid >> 2, sc = (tid & 3) * 8;

  // ---- phase 1: scores S[64][256] in registers ----
  for (int kt = 0; kt < 2; kt++) {
    const int k0 = kt * 32;
    ushort8 av = *(const ushort8*)(Qb + (m0 + sr) * 64 + k0 + sc);
    ushort8 bv[4];
#pragma unroll
    for (int r = 0; r < 4; r++) {
      int c = r * 256 + tid;
      bv[r] = *(const ushort8*)(Kb + (c >> 2) * 64 + k0 + (c & 3) * 8);
    }
    __syncthreads();
    *(ushort8*)(&As[sr][sc]) = av;
#pragma unroll
    for (int r = 0; r < 4; r++) {
      int c = r * 256 + tid;
      *(ushort8*)(&Bs[c >> 2][(c & 3) * 8]) = bv[r];
    }
    __syncthreads();
    bf16x8 af = *(const bf16x8*)(&As[w * 16 + l15][quad * 8]);
#pragma unroll
    for (int j = 0; j < 16; j++) {
      bf16x8 bfj = *(const bf16x8*)(&Bs[j * 16 + l15][quad * 8]);
      acc[j] = __builtin_amdgcn_mfma_f32_16x16x32_bf16(af, bfj, acc[j], 0, 0, 0);
    }
  }

  // ---- phase 2: softmax over 256 landmarks, P -> LDS (D-layout -> A-layout)
  __syncthreads();
#pragma unroll
  for (int r = 0; r < 4; r++) {
    float x[16];
    float vmax = -1e30f;
#pragma unroll
    for (int j = 0; j < 16; j++) { x[j] = acc[j][r] * 0.125f; vmax = fmaxf(vmax, x[j]); }
#pragma unroll
    for (int m = 1; m < 16; m <<= 1) vmax = fmaxf(vmax, __shfl_xor(vmax, m, 64));
    float s = 0.f;
#pragma unroll
    for (int j = 0; j < 16; j++) { x[j] = __expf(x[j] - vmax); s += x[j]; }
#pragma unroll
    for (int m = 1; m < 16; m <<= 1) s += __shfl_xor(s, m, 64);
    float inv = 1.0f / s;
    int row = w * 16 + quad * 4 + r;
#pragma unroll
    for (int j = 0; j < 16; j++)
      P[row][j * 16 + l15] = f2bf(x[j] * inv);
  }
  __syncthreads();

  // ---- phase 3: O[64][64] = P @ VlmT^T ----
  f32x4 o_acc[4];
#pragma unroll
  for (int j = 0; j < 4; j++) o_acc[j] = zz;
#pragma unroll
  for (int kc = 0; kc < 8; kc++) {
    bf16x8 pf = *(const bf16x8*)(&P[w * 16 + l15][kc * 32 + quad * 8]);
#pragma unroll
    for (int j = 0; j < 4; j++) {
      bf16x8 vf = *(const bf16x8*)(Vb + (j * 16 + l15) * 256 + kc * 32 + quad * 8);
      o_acc[j] = __builtin_amdgcn_mfma_f32_16x16x32_bf16(pf, vf, o_acc[j], 0, 0, 0);
    }
  }

#pragma unroll
  for (int j = 0; j < 4; j++)
#pragma unroll
    for (int r = 0; r < 4; r++) {
      int row = w * 16 + quad * 4 + r;
      int col = j * 16 + l15;
      O[(long long)z * 262144 + (m0 + row) * 64 + col] = f2bf(o_acc[j][r]);
    }
}

// ------------------- 256x256 tile NT GEMM, f32 out (+bias) -----------------
// A [16384][1024] bf16, B [1024][1024] bf16, C [16384][1024] f32.
// Grid: 256 blocks; xcd = lin&7 owns m-tiles [xcd*8, xcd*8+8) x all 4 n.
__global__ __launch_bounds__(512) void gemm_nt_256(
    const ushort_t* __restrict__ A, const ushort_t* __restrict__ B,
    float* __restrict__ C, const float* __restrict__ bias) {
  __shared__ __align__(16) char smem[131072];
  const int lin = blockIdx.x;
  const int xcd = lin & 7, rr_ = lin >> 3;          // rr_ 0..31
  const int mt = xcd * 8 + (rr_ & 7);               // 0..63
  const int nt = rr_ >> 3;                          // 0..3
  const long long m0 = (long long)mt * 256;
  const long long n0 = (long long)nt * 256;

  f32x4 acc[8][4];
  pipe256(A, B, m0, n0, smem, acc);

  const int tid = threadIdx.x, lane = tid & 63, w = tid >> 6;
  const int l15 = lane & 15, quad = lane >> 4;
  const int wm = w >> 2, wn = w & 3;

#pragma unroll
  for (int mh = 0; mh < 2; mh++)
#pragma unroll
    for (int i = 0; i < 4; i++)
#pragma unroll
      for (int nh = 0; nh < 2; nh++)
#pragma unroll
        for (int j = 0; j < 2; j++) {
          long long row = m0 + mh * 128 + wm * 64 + i * 16 + quad * 4;
          long long col = n0 + nh * 128 + wn * 32 + j * 16 + l15;
          float bv = bias[col];
#pragma unroll
          for (int r = 0; r < 4; r++)
            C[(row + r) * 1024 + col] = acc[mh * 4 + i][nh * 2 + j][r] + bv;
        }
}

// ---------------------------------------------------------------------------
extern "C" void kernel_launch(void* const* d_in, const int* in_sizes, int n_in,
                              void* d_out, int out_size, void* d_ws, size_t ws_size,
                              hipStream_t stream) {
  const float* x     = (const float*)d_in[0];
  const float* Wqkv  = (const float*)d_in[1];
  const float* E     = (const float*)d_in[2];
  const float* Wproj = (const float*)d_in[3];
  const float* bproj = (const float*)d_in[4];
  float* out = (float*)d_out;

  char* ws = (char*)d_ws;
  ushort_t* x_bf     = (ushort_t*)(ws + 0);            // 32 MB; later pK/pV, then attn O
  float*    pK       = (float*)   (ws + 0);            // 16 MB (after gemm_qkv)
  float*    pV       = (float*)   (ws + 16777216);     // 16 MB
  ushort_t* wqkv_bf  = (ushort_t*)(ws + 33554432);     //  6 MB
  ushort_t* e_bf     = (ushort_t*)(ws + 39845888);     // 32 MB
  ushort_t* wproj_bf = (ushort_t*)(ws + 73400320);     //  2 MB
  ushort_t* q_bf     = (ushort_t*)(ws + 75497472);     // 32 MB
  ushort_t* kT       = (ushort_t*)(ws + 109051904);    // 32 MB
  ushort_t* vT       = (ushort_t*)(ws + 142606336);    // 32 MB
  ushort_t* klm      = (ushort_t*)(ws + 176160768);    //  2 MB
  ushort_t* vlmT     = (ushort_t*)(ws + 178257920);    //  2 MB
  // total: 180,355,072 bytes

  // 1) fused f32 -> bf16 converts (one dispatch)
  cvt_all<<<36864, 256, 0, stream>>>(x, x_bf, Wqkv, wqkv_bf, E, e_bf, Wproj, wproj_bf);

  // 2) fused QKV GEMM + repack -> q(n,d), kT(d,n), vT(d,n) bf16  [8-phase 256^2]
  gemm_qkv<<<768, 512, 0, stream>>>(x_bf, wqkv_bf, q_bf, kT, vT);

  // 3) landmark partials, split-K over n; XCD remap + counted-vmcnt pipeline
  lm_gemm<<<1024, 256, 0, stream>>>(e_bf, kT, vT, pK, pV);

  // 4) reduce splits -> klm[z][k][d], vlmT[z][d][k]
  lm_reduce<<<dim3(4, 64), 256, 0, stream>>>(pK, pV, klm, vlmT);

  // 5) fused scores+softmax+PV -> attn_out; XCD-chunked 1D grid
  attn_fused<<<4096, 256, 0, stream>>>(q_bf, klm, vlmT, x_bf);

  // 6) out = attn_out @ Wproj^T + bproj  [16384 x 1024] f32  [8-phase 256^2]
  gemm_nt_256<<<256, 512, 0, stream>>>(x_bf, wproj_bf, out, bproj);
}